// Round 4
// baseline (235.605 us; speedup 1.0000x reference)
//
#include <hip/hip_runtime.h>
#include <hip/hip_fp16.h>

// ---------------------------------------------------------------------------
// ReconGNN: out = conv(relu(conv(x@W1^T)+b1) @ W2^T) + b2
// R18: all kernels now < the 40us harness fillBuffer dispatches -> top-5 is
// saturated; no single dominator. Structural fix with solid arithmetic: conv
// waves hold 8 independent 8-lane node-groups; loop trip = max(deg of 8)/4,
// Poisson(16) -> E[max8]~24 vs mean 16 = ~1.5x masked waste. degscat now
// emits a DEGREE-SORTED worklist per 256-node bin (counting sort on the
// degrees it already has in LDS); convs process worklist order -> groups in
// a wave have near-equal degree -> waste ~5%. Numerically bit-identical
// (per-node edge order unchanged; only node->wave assignment moves).
// Pipeline: memset -> binfill(inline detect) -> degscat(inline scan + sort)
//   -> gemm1_mfma(X direct-to-reg, int8+sc1 out) -> conv64 -> gemm2_mfma ->
//   conv40
// Aliases: binbuf==h1q region (dead before gemm1 writes it); sc1 in the tail
// of the same region.
// ---------------------------------------------------------------------------

typedef __attribute__((ext_vector_type(8))) _Float16 half8v;
typedef __attribute__((ext_vector_type(4))) float   float4v;

// ---- bucket edges by destination bin (c>>8); records cached in LDS ----
// record = src | (c&255)<<17   (N <= 131072). Inline int64/int32 detection.
__global__ void k_binfill(const int* __restrict__ ed,
                          int* __restrict__ gbincnt, unsigned* __restrict__ binbuf,
                          int E, int cap) {
  __shared__ int hist[512];
  __shared__ int cursor[512];
  __shared__ unsigned rec[4096];         // 16 KB
  __shared__ unsigned short binv[4096];  // 8 KB
  __shared__ int s_is64;
  int t = threadIdx.x;
  hist[t] = 0; hist[t + 256] = 0;
  if (t == 0) s_is64 = 1;
  __syncthreads();
  {   // same sample in every block -> same decision (L2-hot after block 0)
    int any = 0;
    #pragma unroll
    for (int u = 0; u < 8; ++u) {
      int idx = 2 * (t * 8 + u) + 1;          // odd words 1..4095
      if (idx < 2 * E && ed[idx] != 0) any = 1;
    }
    if (any) s_is64 = 0;                      // benign race
  }
  __syncthreads();
  const int is64 = s_is64;
  const int base = blockIdx.x * 4096;
  const int nE = min(4096, E - base);
  for (int j = t; j < nE; j += 256) {
    int e = base + j;
    int r = is64 ? ed[2 * e] : ed[e];
    int c = is64 ? ed[2 * (E + e)] : ed[E + e];
    rec[j] = (unsigned)r | ((unsigned)(c & 255) << 17);
    binv[j] = (unsigned short)(c >> 8);
    atomicAdd(&hist[c >> 8], 1);
  }
  __syncthreads();
  for (int b = t; b < 512; b += 256) {
    int h = hist[b];
    cursor[b] = h ? atomicAdd(&gbincnt[b], h) : 0;
  }
  __syncthreads();
  for (int j = t; j < nE; j += 256) {
    int bin = binv[j];
    int pos = atomicAdd(&cursor[bin], 1);
    if (pos < cap)
      binbuf[(size_t)bin * cap + pos] = rec[j];
  }
}

// ---- fused: bin-count prefix (inline) + per-bin degree/scan -> dis/rowptr,
//      then scatter srcs + emit degree-sorted worklist. ----
__global__ void k_degscat(const unsigned* __restrict__ binbuf, const int* __restrict__ gbincnt,
                          float* __restrict__ dis, int* __restrict__ rowptr,
                          int* __restrict__ srcs, int* __restrict__ worklist,
                          int NBINS, int N, int cap) {
  __shared__ int sd[512];          // global bin-count prefix
  __shared__ int cnt[256];
  __shared__ int sc[256];
  __shared__ int cursor[256];
  __shared__ int dh[256];          // degree histogram (sort)
  __shared__ int dsc[256];         // degree prefix
  __shared__ int dcur[256];        // degree cursors
  __shared__ unsigned rec[8192];   // 32 KB
  int t = threadIdx.x, b = blockIdx.x;
  sd[t]       = (t < NBINS)       ? min(gbincnt[t], cap)       : 0;
  sd[t + 256] = (t + 256 < NBINS) ? min(gbincnt[t + 256], cap) : 0;
  cnt[t] = 0; dh[t] = 0; dcur[t] = 0;
  __syncthreads();
  for (int off = 1; off < 512; off <<= 1) {
    int v0 = (t >= off) ? sd[t - off] : 0;
    int v1 = sd[t + 256 - off];
    __syncthreads();
    sd[t] += v0; sd[t + 256] += v1;
    __syncthreads();
  }
  const int mybase = (b == 0) ? 0 : sd[b - 1];
  if (b == NBINS - 1 && t == 0) rowptr[N] = sd[NBINS - 1];

  int n = min(gbincnt[b], cap);
  const unsigned* buf = binbuf + (size_t)b * cap;
  for (int j = t; j < n; j += 256) {
    unsigned v = buf[j];
    rec[j] = v;
    atomicAdd(&cnt[v >> 17], 1);
  }
  __syncthreads();
  sc[t] = cnt[t];
  __syncthreads();
  for (int off = 1; off < 256; off <<= 1) {
    int v = (t >= off) ? sc[t - off] : 0;
    __syncthreads();
    sc[t] += v;
    __syncthreads();
  }
  int rp = mybase + ((t == 0) ? 0 : sc[t - 1]);
  cursor[t] = rp;
  int node = b * 256 + t;
  bool valid = node < N;
  if (valid) {
    int d = cnt[t];
    dis[node] = (d > 0) ? rsqrtf((float)d) : 0.f;
    rowptr[node] = rp;
  }
  __syncthreads();
  for (int j = t; j < n; j += 256) {
    unsigned v = rec[j];
    int pos = atomicAdd(&cursor[v >> 17], 1);
    srcs[pos] = (int)(v & 0x1FFFF);
  }

  // ---- degree-sorted worklist: counting sort of this bin's 256 nodes ----
  int db = valid ? min(cnt[t], 254) : 255;   // invalid nodes sort last
  atomicAdd(&dh[db], 1);
  __syncthreads();
  dsc[t] = dh[t];
  __syncthreads();
  for (int off = 1; off < 256; off <<= 1) {
    int v = (t >= off) ? dsc[t - off] : 0;
    __syncthreads();
    dsc[t] += v;
    __syncthreads();
  }
  int rbase = (db == 0) ? 0 : dsc[db - 1];
  int rank = rbase + atomicAdd(&dcur[db], 1);
  worklist[b * 256 + rank] = valid ? node : 0x7FFFFFFF;
}

// ---- gemm1 (MFMA f16): h1 rows = int8((X[N][128] @ W[64][128]^T)*dis),
//      per-row fp32 scale in separate sc1[N] (row = exactly one 64B line).
//      X: direct global->register A-fragments (no LDS, no reuse to exploit).
//      W: LDS fp16 swizzled (shared by all waves), one barrier.
__launch_bounds__(256)
__global__ void k_gemm1_mfma(const float* __restrict__ X, const float* __restrict__ W,
                             const float* __restrict__ dis, unsigned char* __restrict__ h1q,
                             float* __restrict__ sc1, int N) {
  __shared__ _Float16 wl[64 * 128];    // 16 KB
  const int t = threadIdx.x;
  const int row0 = blockIdx.x * 128;
  const int w = t >> 6, l = t & 63;
  const int m0 = w * 32;
  const int lr = l & 15, q = l >> 4;

  // issue all X fragment loads first: 16 independent float4 HBM streams.
  // lane (lr,q) reads rows m0+mt*16+lr, cols kc*32+q*8 .. +7 (32B contig).
  float4 xr[4][2][2];   // [kc][mt][half]
  #pragma unroll
  for (int kc = 0; kc < 4; ++kc) {
    #pragma unroll
    for (int mt = 0; mt < 2; ++mt) {
      int row = min(row0 + m0 + mt * 16 + lr, N - 1);   // clamp: OOB rows read
      const float* p = &X[(size_t)row * 128 + kc * 32 + q * 8];  // valid mem,
      xr[kc][mt][0] = *(const float4*)p;                // masked at epilogue
      xr[kc][mt][1] = *(const float4*)(p + 4);
    }
  }

  // stage W (64x128) to LDS fp16, swizzled (reused by every wave)
  #pragma unroll
  for (int j = 0; j < 8; ++j) {
    int qq = t + 256 * j;
    int r = qq >> 5, k4 = qq & 31;
    float4 v = *(const float4*)&W[(size_t)r * 128 + k4 * 4];
    _Float16 h4[4] = {(_Float16)v.x, (_Float16)v.y, (_Float16)v.z, (_Float16)v.w};
    int k = (k4 * 4) ^ ((r & 7) * 8);
    *(float2*)&wl[r * 128 + k] = *(float2*)h4;
  }
  __syncthreads();

  float4v acc[2][4] = {};
  #pragma unroll
  for (int kc = 0; kc < 4; ++kc) {
    half8v a[2], b[4];
    #pragma unroll
    for (int mt = 0; mt < 2; ++mt) {
      float4 v0 = xr[kc][mt][0], v1 = xr[kc][mt][1];
      _Float16 h8[8] = {(_Float16)v0.x, (_Float16)v0.y, (_Float16)v0.z, (_Float16)v0.w,
                        (_Float16)v1.x, (_Float16)v1.y, (_Float16)v1.z, (_Float16)v1.w};
      a[mt] = *(half8v*)h8;
    }
    #pragma unroll
    for (int nt = 0; nt < 4; ++nt) {
      int n = nt * 16 + lr;
      int k = (kc * 32 + q * 8) ^ ((n & 7) * 8);
      b[nt] = *(half8v*)&wl[n * 128 + k];
    }
    #pragma unroll
    for (int mt = 0; mt < 2; ++mt)
      #pragma unroll
      for (int nt = 0; nt < 4; ++nt)
        acc[mt][nt] = __builtin_amdgcn_mfma_f32_16x16x32_f16(a[mt], b[nt], acc[mt][nt], 0, 0, 0);
  }

  // epilogue: per row (16-lane group, same q) reduce rowmax, quantize int8.
  #pragma unroll
  for (int mt = 0; mt < 2; ++mt) {
    #pragma unroll
    for (int r = 0; r < 4; ++r) {
      int row = row0 + m0 + mt * 16 + q * 4 + r;
      if (row < N) {                         // uniform within 16-lane group
        float dr = dis[row];
        float v0 = acc[mt][0][r] * dr;
        float v1 = acc[mt][1][r] * dr;
        float v2 = acc[mt][2][r] * dr;
        float v3 = acc[mt][3][r] * dr;
        float m = fmaxf(fmaxf(fabsf(v0), fabsf(v1)), fmaxf(fabsf(v2), fabsf(v3)));
        #pragma unroll
        for (int off = 1; off < 16; off <<= 1)
          m = fmaxf(m, __shfl_xor(m, off));   // stays within 16-lane group
        float inv = (m > 0.f) ? (127.f / m) : 0.f;
        unsigned char* dst = h1q + (size_t)row * 64;
        int q0 = (int)rintf(v0 * inv);
        int q1 = (int)rintf(v1 * inv);
        int q2 = (int)rintf(v2 * inv);
        int q3 = (int)rintf(v3 * inv);
        q0 = max(-127, min(127, q0));
        q1 = max(-127, min(127, q1));
        q2 = max(-127, min(127, q2));
        q3 = max(-127, min(127, q3));
        dst[lr]      = (unsigned char)(signed char)q0;
        dst[lr + 16] = (unsigned char)(signed char)q1;
        dst[lr + 32] = (unsigned char)(signed char)q2;
        dst[lr + 48] = (unsigned char)(signed char)q3;
        if (lr == 0) sc1[row] = m * (1.f / 127.f);
      }
    }
  }
}

// ---- gemm2 (MFMA f16): h2 rows = int8((h1b @ W2^T)*dis) + per-row scale ----
// row layout (64B): bytes 0..39 int8 features, 40..43 fp32 scale, 44..63 zero.
__launch_bounds__(256)
__global__ void k_gemm2_mfma(const __half* __restrict__ Xh, const float* __restrict__ W,
                             const float* __restrict__ dis, unsigned char* __restrict__ h2,
                             int N) {
  __shared__ _Float16 xl[128 * 64];   // 16 KB
  __shared__ _Float16 wl[48 * 64];    // 6 KB (rows 40..47 zero)
  const int t = threadIdx.x;
  const int row0 = blockIdx.x * 128;

  for (int i = t; i < 48 * 8; i += 256) {
    int c = i >> 3, kq = i & 7;
    _Float16 h8[8];
    #pragma unroll
    for (int j = 0; j < 8; ++j)
      h8[j] = (c < 40) ? (_Float16)W[c * 64 + kq * 8 + j] : (_Float16)0.f;
    *(float4*)&wl[c * 64 + ((kq * 8) ^ ((c & 7) * 8))] = *(float4*)h8;
  }
  for (int i = t; i < 1024; i += 256) {
    int r = i >> 3, kq = i & 7;
    int row = row0 + r;
    float4 v = make_float4(0.f, 0.f, 0.f, 0.f);
    if (row < N) v = *(const float4*)&Xh[(size_t)row * 64 + kq * 8];
    *(float4*)&xl[r * 64 + ((kq * 8) ^ ((r & 7) * 8))] = v;
  }
  __syncthreads();

  const int w = t >> 6, l = t & 63;
  const int m0 = w * 32;
  const int lr = l & 15, q = l >> 4;

  float4v acc[2][3] = {};
  #pragma unroll
  for (int kc = 0; kc < 2; ++kc) {
    half8v a[2], b[3];
    #pragma unroll
    for (int mt = 0; mt < 2; ++mt) {
      int m = m0 + mt * 16 + lr;
      int k = (kc * 32 + q * 8) ^ ((m & 7) * 8);
      a[mt] = *(half8v*)&xl[m * 64 + k];
    }
    #pragma unroll
    for (int nt = 0; nt < 3; ++nt) {
      int n = nt * 16 + lr;
      int k = (kc * 32 + q * 8) ^ ((n & 7) * 8);
      b[nt] = *(half8v*)&wl[n * 64 + k];
    }
    #pragma unroll
    for (int mt = 0; mt < 2; ++mt)
      #pragma unroll
      for (int nt = 0; nt < 3; ++nt)
        acc[mt][nt] = __builtin_amdgcn_mfma_f32_16x16x32_f16(a[mt], b[nt], acc[mt][nt], 0, 0, 0);
  }

  // epilogue: per row (16-lane group, same q) reduce rowmax, quantize int8.
  // cols 40..47 are zero (W zero-padded) so including them is safe.
  #pragma unroll
  for (int mt = 0; mt < 2; ++mt) {
    #pragma unroll
    for (int r = 0; r < 4; ++r) {
      int row = row0 + m0 + mt * 16 + q * 4 + r;
      if (row < N) {
        float dr = dis[row];
        float v0 = acc[mt][0][r] * dr;
        float v1 = acc[mt][1][r] * dr;
        float v2 = acc[mt][2][r] * dr;
        float m = fmaxf(fabsf(v0), fmaxf(fabsf(v1), fabsf(v2)));
        #pragma unroll
        for (int off = 1; off < 16; off <<= 1)
          m = fmaxf(m, __shfl_xor(m, off));     // stays within 16-lane group
        float s = m * (1.f / 127.f);
        float inv = (m > 0.f) ? (127.f / m) : 0.f;
        unsigned char* dst = h2 + (size_t)row * 64;
        int q0 = (int)rintf(v0 * inv);
        int q1 = (int)rintf(v1 * inv);
        int q2 = (int)rintf(v2 * inv);
        q0 = max(-127, min(127, q0));
        q1 = max(-127, min(127, q1));
        q2 = max(-127, min(127, q2));
        dst[lr]      = (unsigned char)(signed char)q0;
        dst[lr + 16] = (unsigned char)(signed char)q1;
        if (lr + 32 < 40) dst[lr + 32] = (unsigned char)(signed char)q2;
        if (lr == 0) *(float*)&dst[40] = s;
        if (lr >= 1 && lr <= 5) *(int*)&dst[40 + 4 * lr] = 0;   // bytes 44..63
      }
    }
  }
}

// ---- conv1 (D=64, int8+sc1 in = 1 line/edge): 8 lanes per node via
//      degree-sorted worklist (wave's 8 groups have ~equal degree). ----
__launch_bounds__(256)
__global__ void k_conv64(const unsigned char* __restrict__ H, const float* __restrict__ sc1,
                         const int* __restrict__ rowptr, const int* __restrict__ srcs,
                         const int* __restrict__ worklist,
                         const float* __restrict__ dis, const float* __restrict__ b1,
                         __half* __restrict__ out, int N) {
  int t = threadIdx.x;
  int li = t & 7;
  int node = worklist[blockIdx.x * 32 + (t >> 3)];
  if (node < N) {                        // sentinel 0x7FFFFFFF skips
    int s = rowptr[node], e = rowptr[node + 1];
    int last = e - 1;
    float a0 = 0.f, a1 = 0.f, a2 = 0.f, a3 = 0.f,
          a4 = 0.f, a5 = 0.f, a6 = 0.f, a7 = 0.f;
    for (int p = s; p < e; p += 4) {
      int s0 = srcs[p];
      int s1 = srcs[min(p + 1, last)];
      int s2 = srcs[min(p + 2, last)];
      int s3 = srcs[min(p + 3, last)];
      uint2 r0 = *(const uint2*)&H[(size_t)s0 * 64 + 8 * li];
      uint2 r1 = *(const uint2*)&H[(size_t)s1 * 64 + 8 * li];
      uint2 r2 = *(const uint2*)&H[(size_t)s2 * 64 + 8 * li];
      uint2 r3 = *(const uint2*)&H[(size_t)s3 * 64 + 8 * li];
      float c0 = sc1[s0], c1 = sc1[s1], c2 = sc1[s2], c3 = sc1[s3];
      {
        int x0 = (int)r0.x, x1 = (int)r0.y;
        a0 = fmaf((float)((x0 << 24) >> 24), c0, a0);
        a1 = fmaf((float)((x0 << 16) >> 24), c0, a1);
        a2 = fmaf((float)((x0 << 8)  >> 24), c0, a2);
        a3 = fmaf((float)( x0        >> 24), c0, a3);
        a4 = fmaf((float)((x1 << 24) >> 24), c0, a4);
        a5 = fmaf((float)((x1 << 16) >> 24), c0, a5);
        a6 = fmaf((float)((x1 << 8)  >> 24), c0, a6);
        a7 = fmaf((float)( x1        >> 24), c0, a7);
      }
      if (p + 1 < e) {
        int x0 = (int)r1.x, x1 = (int)r1.y;
        a0 = fmaf((float)((x0 << 24) >> 24), c1, a0);
        a1 = fmaf((float)((x0 << 16) >> 24), c1, a1);
        a2 = fmaf((float)((x0 << 8)  >> 24), c1, a2);
        a3 = fmaf((float)( x0        >> 24), c1, a3);
        a4 = fmaf((float)((x1 << 24) >> 24), c1, a4);
        a5 = fmaf((float)((x1 << 16) >> 24), c1, a5);
        a6 = fmaf((float)((x1 << 8)  >> 24), c1, a6);
        a7 = fmaf((float)( x1        >> 24), c1, a7);
      }
      if (p + 2 < e) {
        int x0 = (int)r2.x, x1 = (int)r2.y;
        a0 = fmaf((float)((x0 << 24) >> 24), c2, a0);
        a1 = fmaf((float)((x0 << 16) >> 24), c2, a1);
        a2 = fmaf((float)((x0 << 8)  >> 24), c2, a2);
        a3 = fmaf((float)( x0        >> 24), c2, a3);
        a4 = fmaf((float)((x1 << 24) >> 24), c2, a4);
        a5 = fmaf((float)((x1 << 16) >> 24), c2, a5);
        a6 = fmaf((float)((x1 << 8)  >> 24), c2, a6);
        a7 = fmaf((float)( x1        >> 24), c2, a7);
      }
      if (p + 3 < e) {
        int x0 = (int)r3.x, x1 = (int)r3.y;
        a0 = fmaf((float)((x0 << 24) >> 24), c3, a0);
        a1 = fmaf((float)((x0 << 16) >> 24), c3, a1);
        a2 = fmaf((float)((x0 << 8)  >> 24), c3, a2);
        a3 = fmaf((float)( x0        >> 24), c3, a3);
        a4 = fmaf((float)((x1 << 24) >> 24), c3, a4);
        a5 = fmaf((float)((x1 << 16) >> 24), c3, a5);
        a6 = fmaf((float)((x1 << 8)  >> 24), c3, a6);
        a7 = fmaf((float)( x1        >> 24), c3, a7);
      }
    }
    float dn = dis[node];
    const float* bb = b1 + 8 * li;
    __half hv[8];
    hv[0] = __float2half_rn(fmaxf(fmaf(a0, dn, bb[0]), 0.f));
    hv[1] = __float2half_rn(fmaxf(fmaf(a1, dn, bb[1]), 0.f));
    hv[2] = __float2half_rn(fmaxf(fmaf(a2, dn, bb[2]), 0.f));
    hv[3] = __float2half_rn(fmaxf(fmaf(a3, dn, bb[3]), 0.f));
    hv[4] = __float2half_rn(fmaxf(fmaf(a4, dn, bb[4]), 0.f));
    hv[5] = __float2half_rn(fmaxf(fmaf(a5, dn, bb[5]), 0.f));
    hv[6] = __float2half_rn(fmaxf(fmaf(a6, dn, bb[6]), 0.f));
    hv[7] = __float2half_rn(fmaxf(fmaf(a7, dn, bb[7]), 0.f));
    *(float4*)&out[(size_t)node * 64 + 8 * li] = *(float4*)hv;
  }
}

// ---- conv2 (int8+scale in, 64B rows = 1 line/edge; fp32 out): 8 lanes per
//      node via degree-sorted worklist, scale from same cache line. ----
__launch_bounds__(256)
__global__ void k_conv40(const unsigned char* __restrict__ H, const int* __restrict__ rowptr,
                         const int* __restrict__ srcs, const int* __restrict__ worklist,
                         const float* __restrict__ dis, const float* __restrict__ b2,
                         float* __restrict__ out, int N) {
  int t = threadIdx.x;
  int li = t & 7;
  int node = worklist[blockIdx.x * 32 + (t >> 3)];
  if (node < N) {
    bool act = li < 5;
    int s = rowptr[node], e = rowptr[node + 1];
    int last = e - 1;
    float a0 = 0.f, a1 = 0.f, a2 = 0.f, a3 = 0.f,
          a4 = 0.f, a5 = 0.f, a6 = 0.f, a7 = 0.f;
    for (int p = s; p < e; p += 4) {
      int s0 = srcs[p];
      int s1 = srcs[min(p + 1, last)];
      int s2 = srcs[min(p + 2, last)];
      int s3 = srcs[min(p + 3, last)];
      if (act) {
        const unsigned char* p0 = &H[(size_t)s0 * 64];
        const unsigned char* p1 = &H[(size_t)s1 * 64];
        const unsigned char* p2 = &H[(size_t)s2 * 64];
        const unsigned char* p3 = &H[(size_t)s3 * 64];
        uint2 r0 = *(const uint2*)&p0[8 * li];
        uint2 r1 = *(const uint2*)&p1[8 * li];
        uint2 r2 = *(const uint2*)&p2[8 * li];
        uint2 r3 = *(const uint2*)&p3[8 * li];
        float c0 = *(const float*)&p0[40];
        float c1 = *(const float*)&p1[40];
        float c2 = *(const float*)&p2[40];
        float c3 = *(const float*)&p3[40];
        {
          int x0 = (int)r0.x, x1 = (int)r0.y;
          a0 = fmaf((float)((x0 << 24) >> 24), c0, a0);
          a1 = fmaf((float)((x0 << 16) >> 24), c0, a1);
          a2 = fmaf((float)((x0 << 8)  >> 24), c0, a2);
          a3 = fmaf((float)( x0        >> 24), c0, a3);
          a4 = fmaf((float)((x1 << 24) >> 24), c0, a4);
          a5 = fmaf((float)((x1 << 16) >> 24), c0, a5);
          a6 = fmaf((float)((x1 << 8)  >> 24), c0, a6);
          a7 = fmaf((float)( x1        >> 24), c0, a7);
        }
        if (p + 1 < e) {
          int x0 = (int)r1.x, x1 = (int)r1.y;
          a0 = fmaf((float)((x0 << 24) >> 24), c1, a0);
          a1 = fmaf((float)((x0 << 16) >> 24), c1, a1);
          a2 = fmaf((float)((x0 << 8)  >> 24), c1, a2);
          a3 = fmaf((float)( x0        >> 24), c1, a3);
          a4 = fmaf((float)((x1 << 24) >> 24), c1, a4);
          a5 = fmaf((float)((x1 << 16) >> 24), c1, a5);
          a6 = fmaf((float)((x1 << 8)  >> 24), c1, a6);
          a7 = fmaf((float)( x1        >> 24), c1, a7);
        }
        if (p + 2 < e) {
          int x0 = (int)r2.x, x1 = (int)r2.y;
          a0 = fmaf((float)((x0 << 24) >> 24), c2, a0);
          a1 = fmaf((float)((x0 << 16) >> 24), c2, a1);
          a2 = fmaf((float)((x0 << 8)  >> 24), c2, a2);
          a3 = fmaf((float)( x0        >> 24), c2, a3);
          a4 = fmaf((float)((x1 << 24) >> 24), c2, a4);
          a5 = fmaf((float)((x1 << 16) >> 24), c2, a5);
          a6 = fmaf((float)((x1 << 8)  >> 24), c2, a6);
          a7 = fmaf((float)( x1        >> 24), c2, a7);
        }
        if (p + 3 < e) {
          int x0 = (int)r3.x, x1 = (int)r3.y;
          a0 = fmaf((float)((x0 << 24) >> 24), c3, a0);
          a1 = fmaf((float)((x0 << 16) >> 24), c3, a1);
          a2 = fmaf((float)((x0 << 8)  >> 24), c3, a2);
          a3 = fmaf((float)( x0        >> 24), c3, a3);
          a4 = fmaf((float)((x1 << 24) >> 24), c3, a4);
          a5 = fmaf((float)((x1 << 16) >> 24), c3, a5);
          a6 = fmaf((float)((x1 << 8)  >> 24), c3, a6);
          a7 = fmaf((float)( x1        >> 24), c3, a7);
        }
      }
    }
    if (act) {                           // features 8*li..8*li+7 (0..39)
      float dn = dis[node];
      const float* bb = b2 + 8 * li;
      float4 v0 = make_float4(fmaf(a0, dn, bb[0]), fmaf(a1, dn, bb[1]),
                              fmaf(a2, dn, bb[2]), fmaf(a3, dn, bb[3]));
      float4 v1 = make_float4(fmaf(a4, dn, bb[4]), fmaf(a5, dn, bb[5]),
                              fmaf(a6, dn, bb[6]), fmaf(a7, dn, bb[7]));
      *(float4*)&out[(size_t)node * 40 + 8 * li] = v0;
      *(float4*)&out[(size_t)node * 40 + 8 * li + 4] = v1;
    }
  }
}

extern "C" void kernel_launch(void* const* d_in, const int* in_sizes, int n_in,
                              void* d_out, int out_size, void* d_ws, size_t ws_size,
                              hipStream_t stream) {
  const float* x  = (const float*)d_in[0];
  const int*   ed = (const int*)d_in[1];
  const float* W1 = (const float*)d_in[2];
  const float* b1 = (const float*)d_in[3];
  const float* W2 = (const float*)d_in[4];
  const float* b2 = (const float*)d_in[5];
  float* out = (float*)d_out;

  const int FIN = 128, FH = 64;
  const int N = in_sizes[0] / FIN;
  const int E = in_sizes[1] / 2;
  const int NBINS = (N + 255) >> 8;              // 391 (<=512)

  char* ws = (char*)d_ws;
  size_t off = 0;
  auto alloc = [&](size_t bytes) {
    void* p = ws + off;
    off = (off + bytes + 255) & ~(size_t)255;
    return p;
  };
  int*           gbincnt  = (int*)alloc(512 * 4);
  float*         dis      = (float*)alloc((size_t)N * 4);
  int*           rowptr   = (int*)alloc(((size_t)N + 1) * 4);
  int*           srcs     = (int*)alloc((size_t)E * 4);
  int*           worklist = (int*)alloc((size_t)NBINS * 256 * 4);
  unsigned char* h1q      = (unsigned char*)alloc((size_t)N * FH * 2); // also binbuf
  __half*        h1b      = (__half*)alloc((size_t)N * FH * 2);  // conv1 out
  unsigned char* h2       = (unsigned char*)alloc((size_t)N * 64); // int8+scale 64B rows
  // sc1 lives in the tail of the h1q/binbuf region (binbuf dead by gemm1;
  // int8 rows use only the first N*64 bytes of the N*128-byte region)
  float* sc1 = (float*)(h1q + (((size_t)N * 64 + 255) & ~(size_t)255));
  int cap = (int)(((size_t)N * FH * 2) / ((size_t)NBINS * 4));
  if (cap > 8192) cap = 8192;                    // mean bin load ~4092
  unsigned* binbuf = (unsigned*)h1q;             // dead before gemm1 writes h1q

  hipMemsetAsync(gbincnt, 0, 512 * 4, stream);

  int fb = (E + 4095) / 4096;
  k_binfill<<<fb, 256, 0, stream>>>(ed, gbincnt, binbuf, E, cap);
  k_degscat<<<NBINS, 256, 0, stream>>>(binbuf, gbincnt, dis, rowptr, srcs, worklist,
                                       NBINS, N, cap);

  int mb = (N + 127) / 128;
  int cb = NBINS * 8;                            // covers NBINS*256 worklist slots
  k_gemm1_mfma<<<mb, 256, 0, stream>>>(x, W1, dis, h1q, sc1, N);
  k_conv64<<<cb, 256, 0, stream>>>(h1q, sc1, rowptr, srcs, worklist, dis, b1, h1b, N);
  k_gemm2_mfma<<<mb, 256, 0, stream>>>(h1b, W2, dis, h2, N);
  k_conv40<<<cb, 256, 0, stream>>>(h2, rowptr, srcs, worklist, dis, b2, out, N);
}

// Round 5
// 219.372 us; speedup vs baseline: 1.0740x; 1.0740x over previous
//
#include <hip/hip_runtime.h>
#include <hip/hip_fp16.h>

// ---------------------------------------------------------------------------
// ReconGNN: out = conv(relu(conv(x@W1^T)+b1) @ W2^T) + b2
// R19: R18's degree-sorted worklist REGRESSED (FETCH 64->77MB, occ 67->42%):
// node-order adjacency of srcs/rowptr/out was worth more than divergence
// savings. Reverted. R18 counters showed convs latency-bound (VALU 15%,
// HBM 27%, MfmaUtil 0): need ~94 lines in flight/CU, waves held ~12.
// Both convs now unroll 8 EDGES (was 4): 8 srcs + 8 H-lines + 8 sc1 issued
// before any FMA -> ~24 outstanding loads/wave, 2x MLP. Clamped tail slots
// re-hit the last edge's line (L1-hot), so fetch ~unchanged.
// Pipeline: memset -> binfill(inline detect) -> degscat(inline scan) ->
//   gemm1_mfma(X direct-to-reg, int8+sc1 out) -> conv64 -> gemm2_mfma ->
//   conv40
// Aliases: binbuf==h1q region (dead before gemm1 writes it); sc1 in the tail
// of the same region.
// ---------------------------------------------------------------------------

typedef __attribute__((ext_vector_type(8))) _Float16 half8v;
typedef __attribute__((ext_vector_type(4))) float   float4v;

// ---- bucket edges by destination bin (c>>8); records cached in LDS ----
// record = src | (c&255)<<17   (N <= 131072). Inline int64/int32 detection.
__global__ void k_binfill(const int* __restrict__ ed,
                          int* __restrict__ gbincnt, unsigned* __restrict__ binbuf,
                          int E, int cap) {
  __shared__ int hist[512];
  __shared__ int cursor[512];
  __shared__ unsigned rec[4096];         // 16 KB
  __shared__ unsigned short binv[4096];  // 8 KB
  __shared__ int s_is64;
  int t = threadIdx.x;
  hist[t] = 0; hist[t + 256] = 0;
  if (t == 0) s_is64 = 1;
  __syncthreads();
  {   // same sample in every block -> same decision (L2-hot after block 0)
    int any = 0;
    #pragma unroll
    for (int u = 0; u < 8; ++u) {
      int idx = 2 * (t * 8 + u) + 1;          // odd words 1..4095
      if (idx < 2 * E && ed[idx] != 0) any = 1;
    }
    if (any) s_is64 = 0;                      // benign race
  }
  __syncthreads();
  const int is64 = s_is64;
  const int base = blockIdx.x * 4096;
  const int nE = min(4096, E - base);
  for (int j = t; j < nE; j += 256) {
    int e = base + j;
    int r = is64 ? ed[2 * e] : ed[e];
    int c = is64 ? ed[2 * (E + e)] : ed[E + e];
    rec[j] = (unsigned)r | ((unsigned)(c & 255) << 17);
    binv[j] = (unsigned short)(c >> 8);
    atomicAdd(&hist[c >> 8], 1);
  }
  __syncthreads();
  for (int b = t; b < 512; b += 256) {
    int h = hist[b];
    cursor[b] = h ? atomicAdd(&gbincnt[b], h) : 0;
  }
  __syncthreads();
  for (int j = t; j < nE; j += 256) {
    int bin = binv[j];
    int pos = atomicAdd(&cursor[bin], 1);
    if (pos < cap)
      binbuf[(size_t)bin * cap + pos] = rec[j];
  }
}

// ---- fused: bin-count prefix (inline) + per-bin degree/scan -> dis/rowptr,
//      then scatter srcs. Bin records cached in LDS. ----
__global__ void k_degscat(const unsigned* __restrict__ binbuf, const int* __restrict__ gbincnt,
                          float* __restrict__ dis, int* __restrict__ rowptr,
                          int* __restrict__ srcs, int NBINS, int N, int cap) {
  __shared__ int sd[512];          // global bin-count prefix
  __shared__ int cnt[256];
  __shared__ int sc[256];
  __shared__ int cursor[256];
  __shared__ unsigned rec[8192];   // 32 KB
  int t = threadIdx.x, b = blockIdx.x;
  sd[t]       = (t < NBINS)       ? min(gbincnt[t], cap)       : 0;
  sd[t + 256] = (t + 256 < NBINS) ? min(gbincnt[t + 256], cap) : 0;
  cnt[t] = 0;
  __syncthreads();
  for (int off = 1; off < 512; off <<= 1) {
    int v0 = (t >= off) ? sd[t - off] : 0;
    int v1 = sd[t + 256 - off];
    __syncthreads();
    sd[t] += v0; sd[t + 256] += v1;
    __syncthreads();
  }
  const int mybase = (b == 0) ? 0 : sd[b - 1];
  if (b == NBINS - 1 && t == 0) rowptr[N] = sd[NBINS - 1];

  int n = min(gbincnt[b], cap);
  const unsigned* buf = binbuf + (size_t)b * cap;
  for (int j = t; j < n; j += 256) {
    unsigned v = buf[j];
    rec[j] = v;
    atomicAdd(&cnt[v >> 17], 1);
  }
  __syncthreads();
  sc[t] = cnt[t];
  __syncthreads();
  for (int off = 1; off < 256; off <<= 1) {
    int v = (t >= off) ? sc[t - off] : 0;
    __syncthreads();
    sc[t] += v;
    __syncthreads();
  }
  int rp = mybase + ((t == 0) ? 0 : sc[t - 1]);
  cursor[t] = rp;
  int node = b * 256 + t;
  if (node < N) {
    int d = cnt[t];
    dis[node] = (d > 0) ? rsqrtf((float)d) : 0.f;
    rowptr[node] = rp;
  }
  __syncthreads();
  for (int j = t; j < n; j += 256) {
    unsigned v = rec[j];
    int pos = atomicAdd(&cursor[v >> 17], 1);
    srcs[pos] = (int)(v & 0x1FFFF);
  }
}

// ---- gemm1 (MFMA f16): h1 rows = int8((X[N][128] @ W[64][128]^T)*dis),
//      per-row fp32 scale in separate sc1[N] (row = exactly one 64B line).
//      X: direct global->register A-fragments (no LDS, no reuse to exploit).
//      W: LDS fp16 swizzled (shared by all waves), one barrier.
__launch_bounds__(256)
__global__ void k_gemm1_mfma(const float* __restrict__ X, const float* __restrict__ W,
                             const float* __restrict__ dis, unsigned char* __restrict__ h1q,
                             float* __restrict__ sc1, int N) {
  __shared__ _Float16 wl[64 * 128];    // 16 KB
  const int t = threadIdx.x;
  const int row0 = blockIdx.x * 128;
  const int w = t >> 6, l = t & 63;
  const int m0 = w * 32;
  const int lr = l & 15, q = l >> 4;

  // issue all X fragment loads first: 16 independent float4 HBM streams.
  // lane (lr,q) reads rows m0+mt*16+lr, cols kc*32+q*8 .. +7 (32B contig).
  float4 xr[4][2][2];   // [kc][mt][half]
  #pragma unroll
  for (int kc = 0; kc < 4; ++kc) {
    #pragma unroll
    for (int mt = 0; mt < 2; ++mt) {
      int row = min(row0 + m0 + mt * 16 + lr, N - 1);   // clamp: OOB rows read
      const float* p = &X[(size_t)row * 128 + kc * 32 + q * 8];  // valid mem,
      xr[kc][mt][0] = *(const float4*)p;                // masked at epilogue
      xr[kc][mt][1] = *(const float4*)(p + 4);
    }
  }

  // stage W (64x128) to LDS fp16, swizzled (reused by every wave)
  #pragma unroll
  for (int j = 0; j < 8; ++j) {
    int qq = t + 256 * j;
    int r = qq >> 5, k4 = qq & 31;
    float4 v = *(const float4*)&W[(size_t)r * 128 + k4 * 4];
    _Float16 h4[4] = {(_Float16)v.x, (_Float16)v.y, (_Float16)v.z, (_Float16)v.w};
    int k = (k4 * 4) ^ ((r & 7) * 8);
    *(float2*)&wl[r * 128 + k] = *(float2*)h4;
  }
  __syncthreads();

  float4v acc[2][4] = {};
  #pragma unroll
  for (int kc = 0; kc < 4; ++kc) {
    half8v a[2], b[4];
    #pragma unroll
    for (int mt = 0; mt < 2; ++mt) {
      float4 v0 = xr[kc][mt][0], v1 = xr[kc][mt][1];
      _Float16 h8[8] = {(_Float16)v0.x, (_Float16)v0.y, (_Float16)v0.z, (_Float16)v0.w,
                        (_Float16)v1.x, (_Float16)v1.y, (_Float16)v1.z, (_Float16)v1.w};
      a[mt] = *(half8v*)h8;
    }
    #pragma unroll
    for (int nt = 0; nt < 4; ++nt) {
      int n = nt * 16 + lr;
      int k = (kc * 32 + q * 8) ^ ((n & 7) * 8);
      b[nt] = *(half8v*)&wl[n * 128 + k];
    }
    #pragma unroll
    for (int mt = 0; mt < 2; ++mt)
      #pragma unroll
      for (int nt = 0; nt < 4; ++nt)
        acc[mt][nt] = __builtin_amdgcn_mfma_f32_16x16x32_f16(a[mt], b[nt], acc[mt][nt], 0, 0, 0);
  }

  // epilogue: per row (16-lane group, same q) reduce rowmax, quantize int8.
  #pragma unroll
  for (int mt = 0; mt < 2; ++mt) {
    #pragma unroll
    for (int r = 0; r < 4; ++r) {
      int row = row0 + m0 + mt * 16 + q * 4 + r;
      if (row < N) {                         // uniform within 16-lane group
        float dr = dis[row];
        float v0 = acc[mt][0][r] * dr;
        float v1 = acc[mt][1][r] * dr;
        float v2 = acc[mt][2][r] * dr;
        float v3 = acc[mt][3][r] * dr;
        float m = fmaxf(fmaxf(fabsf(v0), fabsf(v1)), fmaxf(fabsf(v2), fabsf(v3)));
        #pragma unroll
        for (int off = 1; off < 16; off <<= 1)
          m = fmaxf(m, __shfl_xor(m, off));   // stays within 16-lane group
        float inv = (m > 0.f) ? (127.f / m) : 0.f;
        unsigned char* dst = h1q + (size_t)row * 64;
        int q0 = (int)rintf(v0 * inv);
        int q1 = (int)rintf(v1 * inv);
        int q2 = (int)rintf(v2 * inv);
        int q3 = (int)rintf(v3 * inv);
        q0 = max(-127, min(127, q0));
        q1 = max(-127, min(127, q1));
        q2 = max(-127, min(127, q2));
        q3 = max(-127, min(127, q3));
        dst[lr]      = (unsigned char)(signed char)q0;
        dst[lr + 16] = (unsigned char)(signed char)q1;
        dst[lr + 32] = (unsigned char)(signed char)q2;
        dst[lr + 48] = (unsigned char)(signed char)q3;
        if (lr == 0) sc1[row] = m * (1.f / 127.f);
      }
    }
  }
}

// ---- gemm2 (MFMA f16): h2 rows = int8((h1b @ W2^T)*dis) + per-row scale ----
// row layout (64B): bytes 0..39 int8 features, 40..43 fp32 scale, 44..63 zero.
__launch_bounds__(256)
__global__ void k_gemm2_mfma(const __half* __restrict__ Xh, const float* __restrict__ W,
                             const float* __restrict__ dis, unsigned char* __restrict__ h2,
                             int N) {
  __shared__ _Float16 xl[128 * 64];   // 16 KB
  __shared__ _Float16 wl[48 * 64];    // 6 KB (rows 40..47 zero)
  const int t = threadIdx.x;
  const int row0 = blockIdx.x * 128;

  for (int i = t; i < 48 * 8; i += 256) {
    int c = i >> 3, kq = i & 7;
    _Float16 h8[8];
    #pragma unroll
    for (int j = 0; j < 8; ++j)
      h8[j] = (c < 40) ? (_Float16)W[c * 64 + kq * 8 + j] : (_Float16)0.f;
    *(float4*)&wl[c * 64 + ((kq * 8) ^ ((c & 7) * 8))] = *(float4*)h8;
  }
  for (int i = t; i < 1024; i += 256) {
    int r = i >> 3, kq = i & 7;
    int row = row0 + r;
    float4 v = make_float4(0.f, 0.f, 0.f, 0.f);
    if (row < N) v = *(const float4*)&Xh[(size_t)row * 64 + kq * 8];
    *(float4*)&xl[r * 64 + ((kq * 8) ^ ((r & 7) * 8))] = v;
  }
  __syncthreads();

  const int w = t >> 6, l = t & 63;
  const int m0 = w * 32;
  const int lr = l & 15, q = l >> 4;

  float4v acc[2][3] = {};
  #pragma unroll
  for (int kc = 0; kc < 2; ++kc) {
    half8v a[2], b[3];
    #pragma unroll
    for (int mt = 0; mt < 2; ++mt) {
      int m = m0 + mt * 16 + lr;
      int k = (kc * 32 + q * 8) ^ ((m & 7) * 8);
      a[mt] = *(half8v*)&xl[m * 64 + k];
    }
    #pragma unroll
    for (int nt = 0; nt < 3; ++nt) {
      int n = nt * 16 + lr;
      int k = (kc * 32 + q * 8) ^ ((n & 7) * 8);
      b[nt] = *(half8v*)&wl[n * 64 + k];
    }
    #pragma unroll
    for (int mt = 0; mt < 2; ++mt)
      #pragma unroll
      for (int nt = 0; nt < 3; ++nt)
        acc[mt][nt] = __builtin_amdgcn_mfma_f32_16x16x32_f16(a[mt], b[nt], acc[mt][nt], 0, 0, 0);
  }

  // epilogue: per row (16-lane group, same q) reduce rowmax, quantize int8.
  // cols 40..47 are zero (W zero-padded) so including them is safe.
  #pragma unroll
  for (int mt = 0; mt < 2; ++mt) {
    #pragma unroll
    for (int r = 0; r < 4; ++r) {
      int row = row0 + m0 + mt * 16 + q * 4 + r;
      if (row < N) {
        float dr = dis[row];
        float v0 = acc[mt][0][r] * dr;
        float v1 = acc[mt][1][r] * dr;
        float v2 = acc[mt][2][r] * dr;
        float m = fmaxf(fabsf(v0), fmaxf(fabsf(v1), fabsf(v2)));
        #pragma unroll
        for (int off = 1; off < 16; off <<= 1)
          m = fmaxf(m, __shfl_xor(m, off));     // stays within 16-lane group
        float s = m * (1.f / 127.f);
        float inv = (m > 0.f) ? (127.f / m) : 0.f;
        unsigned char* dst = h2 + (size_t)row * 64;
        int q0 = (int)rintf(v0 * inv);
        int q1 = (int)rintf(v1 * inv);
        int q2 = (int)rintf(v2 * inv);
        q0 = max(-127, min(127, q0));
        q1 = max(-127, min(127, q1));
        q2 = max(-127, min(127, q2));
        dst[lr]      = (unsigned char)(signed char)q0;
        dst[lr + 16] = (unsigned char)(signed char)q1;
        if (lr + 32 < 40) dst[lr + 32] = (unsigned char)(signed char)q2;
        if (lr == 0) *(float*)&dst[40] = s;
        if (lr >= 1 && lr <= 5) *(int*)&dst[40 + 4 * lr] = 0;   // bytes 44..63
      }
    }
  }
}

// ---- conv1 (D=64, int8+sc1 in = 1 line/edge): 8 lanes per node, lane li
//      owns features 8li..8li+7. srcs via L1 broadcast, NO shuffles, no
//      reduction. 8-edge unroll = ~24 loads in flight per wave. ----
__launch_bounds__(256)
__global__ void k_conv64(const unsigned char* __restrict__ H, const float* __restrict__ sc1,
                         const int* __restrict__ rowptr, const int* __restrict__ srcs,
                         const float* __restrict__ dis, const float* __restrict__ b1,
                         __half* __restrict__ out, int N) {
  int t = threadIdx.x;
  int li = t & 7;
  int node = blockIdx.x * 32 + (t >> 3);
  if (node >= N) return;                 // group-uniform (8-lane groups)
  int s = rowptr[node], e = rowptr[node + 1];
  int last = e - 1;
  float a0 = 0.f, a1 = 0.f, a2 = 0.f, a3 = 0.f,
        a4 = 0.f, a5 = 0.f, a6 = 0.f, a7 = 0.f;
  for (int p = s; p < e; p += 8) {
    int sv[8]; uint2 rv[8]; float cv[8];
    #pragma unroll
    for (int u = 0; u < 8; ++u) sv[u] = srcs[min(p + u, last)];
    #pragma unroll
    for (int u = 0; u < 8; ++u) rv[u] = *(const uint2*)&H[(size_t)sv[u] * 64 + 8 * li];
    #pragma unroll
    for (int u = 0; u < 8; ++u) cv[u] = sc1[sv[u]];
    #pragma unroll
    for (int u = 0; u < 8; ++u) {
      if (p + u < e) {
        int x0 = (int)rv[u].x, x1 = (int)rv[u].y;
        float c = cv[u];
        a0 = fmaf((float)((x0 << 24) >> 24), c, a0);
        a1 = fmaf((float)((x0 << 16) >> 24), c, a1);
        a2 = fmaf((float)((x0 << 8)  >> 24), c, a2);
        a3 = fmaf((float)( x0        >> 24), c, a3);
        a4 = fmaf((float)((x1 << 24) >> 24), c, a4);
        a5 = fmaf((float)((x1 << 16) >> 24), c, a5);
        a6 = fmaf((float)((x1 << 8)  >> 24), c, a6);
        a7 = fmaf((float)( x1        >> 24), c, a7);
      }
    }
  }
  float dn = dis[node];
  const float* bb = b1 + 8 * li;
  __half hv[8];
  hv[0] = __float2half_rn(fmaxf(fmaf(a0, dn, bb[0]), 0.f));
  hv[1] = __float2half_rn(fmaxf(fmaf(a1, dn, bb[1]), 0.f));
  hv[2] = __float2half_rn(fmaxf(fmaf(a2, dn, bb[2]), 0.f));
  hv[3] = __float2half_rn(fmaxf(fmaf(a3, dn, bb[3]), 0.f));
  hv[4] = __float2half_rn(fmaxf(fmaf(a4, dn, bb[4]), 0.f));
  hv[5] = __float2half_rn(fmaxf(fmaf(a5, dn, bb[5]), 0.f));
  hv[6] = __float2half_rn(fmaxf(fmaf(a6, dn, bb[6]), 0.f));
  hv[7] = __float2half_rn(fmaxf(fmaf(a7, dn, bb[7]), 0.f));
  *(float4*)&out[(size_t)node * 64 + 8 * li] = *(float4*)hv;
}

// ---- conv2 (int8+scale in, 64B rows = 1 line/edge; fp32 out): 8 lanes per
//      node, lanes li<5 own features 8li..8li+7, scale from same cache line.
//      8-edge unroll. ----
__launch_bounds__(256)
__global__ void k_conv40(const unsigned char* __restrict__ H, const int* __restrict__ rowptr,
                         const int* __restrict__ srcs, const float* __restrict__ dis,
                         const float* __restrict__ b2, float* __restrict__ out, int N) {
  int t = threadIdx.x;
  int li = t & 7;
  int node = blockIdx.x * 32 + (t >> 3);
  if (node >= N) return;                 // group-uniform
  bool act = li < 5;
  int s = rowptr[node], e = rowptr[node + 1];
  int last = e - 1;
  float a0 = 0.f, a1 = 0.f, a2 = 0.f, a3 = 0.f,
        a4 = 0.f, a5 = 0.f, a6 = 0.f, a7 = 0.f;
  for (int p = s; p < e; p += 8) {
    int sv[8];
    #pragma unroll
    for (int u = 0; u < 8; ++u) sv[u] = srcs[min(p + u, last)];
    if (act) {
      uint2 rv[8]; float cv[8];
      #pragma unroll
      for (int u = 0; u < 8; ++u)
        rv[u] = *(const uint2*)&H[(size_t)sv[u] * 64 + 8 * li];
      #pragma unroll
      for (int u = 0; u < 8; ++u)
        cv[u] = *(const float*)&H[(size_t)sv[u] * 64 + 40];   // same cache line
      #pragma unroll
      for (int u = 0; u < 8; ++u) {
        if (p + u < e) {
          int x0 = (int)rv[u].x, x1 = (int)rv[u].y;
          float c = cv[u];
          a0 = fmaf((float)((x0 << 24) >> 24), c, a0);
          a1 = fmaf((float)((x0 << 16) >> 24), c, a1);
          a2 = fmaf((float)((x0 << 8)  >> 24), c, a2);
          a3 = fmaf((float)( x0        >> 24), c, a3);
          a4 = fmaf((float)((x1 << 24) >> 24), c, a4);
          a5 = fmaf((float)((x1 << 16) >> 24), c, a5);
          a6 = fmaf((float)((x1 << 8)  >> 24), c, a6);
          a7 = fmaf((float)( x1        >> 24), c, a7);
        }
      }
    }
  }
  if (act) {                             // features 8*li..8*li+7 (0..39)
    float dn = dis[node];
    const float* bb = b2 + 8 * li;
    float4 v0 = make_float4(fmaf(a0, dn, bb[0]), fmaf(a1, dn, bb[1]),
                            fmaf(a2, dn, bb[2]), fmaf(a3, dn, bb[3]));
    float4 v1 = make_float4(fmaf(a4, dn, bb[4]), fmaf(a5, dn, bb[5]),
                            fmaf(a6, dn, bb[6]), fmaf(a7, dn, bb[7]));
    *(float4*)&out[(size_t)node * 40 + 8 * li] = v0;
    *(float4*)&out[(size_t)node * 40 + 8 * li + 4] = v1;
  }
}

extern "C" void kernel_launch(void* const* d_in, const int* in_sizes, int n_in,
                              void* d_out, int out_size, void* d_ws, size_t ws_size,
                              hipStream_t stream) {
  const float* x  = (const float*)d_in[0];
  const int*   ed = (const int*)d_in[1];
  const float* W1 = (const float*)d_in[2];
  const float* b1 = (const float*)d_in[3];
  const float* W2 = (const float*)d_in[4];
  const float* b2 = (const float*)d_in[5];
  float* out = (float*)d_out;

  const int FIN = 128, FH = 64;
  const int N = in_sizes[0] / FIN;
  const int E = in_sizes[1] / 2;
  const int NBINS = (N + 255) >> 8;              // 391 (<=512)

  char* ws = (char*)d_ws;
  size_t off = 0;
  auto alloc = [&](size_t bytes) {
    void* p = ws + off;
    off = (off + bytes + 255) & ~(size_t)255;
    return p;
  };
  int*           gbincnt = (int*)alloc(512 * 4);
  float*         dis     = (float*)alloc((size_t)N * 4);
  int*           rowptr  = (int*)alloc(((size_t)N + 1) * 4);
  int*           srcs    = (int*)alloc((size_t)E * 4);
  unsigned char* h1q     = (unsigned char*)alloc((size_t)N * FH * 2); // also binbuf
  __half*        h1b     = (__half*)alloc((size_t)N * FH * 2);  // conv1 out
  unsigned char* h2      = (unsigned char*)alloc((size_t)N * 64); // int8+scale 64B rows
  // sc1 lives in the tail of the h1q/binbuf region (binbuf dead by gemm1;
  // int8 rows use only the first N*64 bytes of the N*128-byte region)
  float* sc1 = (float*)(h1q + (((size_t)N * 64 + 255) & ~(size_t)255));
  int cap = (int)(((size_t)N * FH * 2) / ((size_t)NBINS * 4));
  if (cap > 8192) cap = 8192;                    // mean bin load ~4092
  unsigned* binbuf = (unsigned*)h1q;             // dead before gemm1 writes h1q

  hipMemsetAsync(gbincnt, 0, 512 * 4, stream);

  int fb = (E + 4095) / 4096;
  k_binfill<<<fb, 256, 0, stream>>>(ed, gbincnt, binbuf, E, cap);
  k_degscat<<<NBINS, 256, 0, stream>>>(binbuf, gbincnt, dis, rowptr, srcs, NBINS, N, cap);

  int mb = (N + 127) / 128;
  int cb = (N + 31) / 32;
  k_gemm1_mfma<<<mb, 256, 0, stream>>>(x, W1, dis, h1q, sc1, N);
  k_conv64<<<cb, 256, 0, stream>>>(h1q, sc1, rowptr, srcs, dis, b1, h1b, N);
  k_gemm2_mfma<<<mb, 256, 0, stream>>>(h1b, W2, dis, h2, N);
  k_conv40<<<cb, 256, 0, stream>>>(h2, rowptr, srcs, dis, b2, out, N);
}